// Round 8
// baseline (265.622 us; speedup 1.0000x reference)
//
#include <hip/hip_runtime.h>
#include <hip/hip_cooperative_groups.h>
#include <math.h>

namespace cgrp = cooperative_groups;

// Problem constants (fixed by the reference setup)
#define B_ 4
#define N_ 6400
#define D_ 32
#define TJ 256          // j-chunk staged in LDS
#define NCHJ 25         // N_/TJ
#define TI 128          // anchors per pass unit (4 waves x 2 i-tiles x 16)
#define CHUNK 256       // compaction chunk
#define NCC 25          // N_/CHUNK
#define GRID_ 512       // 2 blocks/CU guaranteed co-resident (42KB LDS, VGPR<=256)

typedef __attribute__((ext_vector_type(4))) float f32x4;
typedef __attribute__((ext_vector_type(8))) short bf16x8;

static constexpr float MARGIN_ = 0.3f;

// monotone float<->uint map so atomicMax(uint) == float max
__device__ __forceinline__ unsigned fmap(float f) {
    unsigned u = __float_as_uint(f);
    return (u & 0x80000000u) ? ~u : (u | 0x80000000u);
}
__device__ __forceinline__ float funmap(unsigned u) {
    return (u & 0x80000000u) ? __uint_as_float(u ^ 0x80000000u)
                             : __uint_as_float(~u);
}
#define NEG_INF_MAPPED 0x007FFFFFu   // fmap(-inf)

// round-to-nearest-even f32 -> bf16
__device__ __forceinline__ unsigned short f2bf(float f) {
    unsigned u = __float_as_uint(f);
    unsigned r = u + 0x7fffu + ((u >> 16) & 1u);
    return (unsigned short)(r >> 16);
}
__device__ __forceinline__ float bf2f(unsigned short h) {
    return __uint_as_float(((unsigned)h) << 16);
}
// unpack packed bf16 pair (elem even in low 16, odd in high 16)
__device__ __forceinline__ void bf2x(unsigned u, float& e0, float& e1) {
    e0 = __uint_as_float(u << 16);
    e1 = __uint_as_float(u & 0xffff0000u);
}

// ---------------- single cooperative mega-kernel ----------------
// Phase A: compact + gather + normalize + bf16 hi/lo split   (100 units)
// Phase B: MFMA pair pass (verified since R3)                (~1300 units)
// Phase C: combine — one wave per anchor, per-block partials (~3200 units)
// Phase D: block 0 reduces 512 partials -> out[0]
__global__ __launch_bounds__(256, 2) void k_mega(const float* __restrict__ pred,
                                                 const int* __restrict__ gt,
                                                 const int* __restrict__ fg,
                                                 const float* __restrict__ pos_rand,
                                                 unsigned short* __restrict__ hi_g,
                                                 unsigned short* __restrict__ lo_g,
                                                 int* __restrict__ clist,
                                                 int* __restrict__ cgt,
                                                 int* __restrict__ Marr,
                                                 unsigned* __restrict__ bestArr,
                                                 unsigned short* __restrict__ p_cnt,
                                                 float* __restrict__ partV,
                                                 int* __restrict__ partC,
                                                 float* __restrict__ out) {
    cgrp::grid_group grid = cgrp::this_grid();
    int t = threadIdx.x;
    int lane = t & 63, w = t >> 6;

    // LDS rows padded to 80 B (40 shorts): 16-lane frag reads = 2-way banks (free)
    __shared__ __align__(16) unsigned short sc_hi[TJ * 40];  // 20 KB
    __shared__ __align__(16) unsigned short sc_lo[TJ * 40];  // 20 KB
    __shared__ int sg[TJ];                                   // 1 KB
    __shared__ int wsh[4];
    __shared__ int s_off, s_M;
    __shared__ float swv[4];
    __shared__ int swc[4];

    // ======== Phase A: prep ========
    for (int u = blockIdx.x; u < NCC * B_; u += gridDim.x) {
        int c = u % NCC, b = u / NCC;
        int idx = c * CHUNK + t;

        bestArr[b * N_ + idx] = NEG_INF_MAPPED;

        bool flag = fg[b * N_ + idx] != 0;
        unsigned long long m = __ballot(flag);
        int lp = __popcll(m & ((1ull << lane) - 1ull));
        if (lane == 0) wsh[w] = __popcll(m);

        // wave 0: derive all 25 chunk counts of this batch -> prefix + total
        if (w == 0) {
            int pre = 0, tot = 0;
            #pragma unroll
            for (int cc = 0; cc < NCC; ++cc) {
                const int4 v = ((const int4*)(fg + (size_t)b * N_ + cc * CHUNK))[lane];
                int cnt = (v.x != 0) + (v.y != 0) + (v.z != 0) + (v.w != 0);
                #pragma unroll
                for (int o = 1; o < 64; o <<= 1) cnt += __shfl_xor(cnt, o);
                pre += (cc < c) ? cnt : 0;
                tot += cnt;
            }
            if (lane == 0) { s_off = pre; s_M = tot; }
        }
        __syncthreads();
        if (c == 0 && t == 0) Marr[b] = s_M;

        if (flag) {
            int woff = 0;
            #pragma unroll
            for (int k = 0; k < 4; ++k) if (k < w) woff += wsh[k];
            int rank = s_off + woff + lp;
            clist[b * N_ + rank] = idx;
            cgt[b * N_ + rank] = gt[b * N_ + idx];

            const float4* s4 = (const float4*)(pred + ((size_t)b * N_ + idx) * D_);
            float f[32];
            float ssq = 0.0f;
            #pragma unroll
            for (int k = 0; k < 8; ++k) {
                float4 q = s4[k];
                f[k * 4] = q.x; f[k * 4 + 1] = q.y; f[k * 4 + 2] = q.z; f[k * 4 + 3] = q.w;
                ssq += q.x * q.x + q.y * q.y + q.z * q.z + q.w * q.w;
            }
            float inv = 1.0f / fmaxf(sqrtf(ssq), 1e-12f);
            unsigned hw[16], lw[16];
            #pragma unroll
            for (int k = 0; k < 16; ++k) {
                float x0 = f[2 * k] * inv, x1 = f[2 * k + 1] * inv;
                unsigned short h0 = f2bf(x0), h1 = f2bf(x1);
                unsigned short l0 = f2bf(x0 - bf2f(h0)), l1 = f2bf(x1 - bf2f(h1));
                hw[k] = (unsigned)h0 | ((unsigned)h1 << 16);
                lw[k] = (unsigned)l0 | ((unsigned)l1 << 16);
            }
            uint4* dh = (uint4*)(hi_g + ((size_t)b * N_ + rank) * 32);
            uint4* dl = (uint4*)(lo_g + ((size_t)b * N_ + rank) * 32);
            #pragma unroll
            for (int k = 0; k < 4; ++k) {
                dh[k] = make_uint4(hw[4 * k], hw[4 * k + 1], hw[4 * k + 2], hw[4 * k + 3]);
                dl[k] = make_uint4(lw[4 * k], lw[4 * k + 1], lw[4 * k + 2], lw[4 * k + 3]);
            }
        }
        __syncthreads();   // wsh/s_off reused next unit
    }

    grid.sync();

    int Mv[B_];
    #pragma unroll
    for (int b = 0; b < B_; ++b) Mv[b] = Marr[b];

    // ======== Phase B: MFMA pair pass ========
    {
        int njv[B_]; int cumU[B_ + 1]; cumU[0] = 0;
        #pragma unroll
        for (int b = 0; b < B_; ++b) {
            int ni = (Mv[b] + TI - 1) / TI, nj = (Mv[b] + TJ - 1) / TJ;
            njv[b] = nj; cumU[b + 1] = cumU[b] + ni * nj;
        }
        int totU = cumU[B_];
        for (int u = blockIdx.x; u < totU; u += gridDim.x) {
            int b = 0;
            while (u >= cumU[b + 1]) ++b;
            int ul = u - cumU[b];
            int ib = ul / njv[b];
            int jb = ul - ib * njv[b];
            int M = Mv[b];
            int i0 = ib * TI, j0 = jb * TJ;

            {
                int j = j0 + t;
                sg[t] = (j < M) ? cgt[b * N_ + j] : -1;
            }
            {   // stage: thread -> (row = p*64 + t>>2, 16B seg = t&3); coalesced
                int seg = t & 3, r0 = t >> 2;
                #pragma unroll
                for (int p = 0; p < 4; ++p) {
                    int row = p * 64 + r0;
                    int j = j0 + row;
                    uint4 vh = make_uint4(0u, 0u, 0u, 0u), vl = make_uint4(0u, 0u, 0u, 0u);
                    if (j < M) {
                        vh = *(const uint4*)(hi_g + ((size_t)b * N_ + j) * 32 + seg * 8);
                        vl = *(const uint4*)(lo_g + ((size_t)b * N_ + j) * 32 + seg * 8);
                    }
                    *(uint4*)(sc_hi + row * 40 + seg * 8) = vh;
                    *(uint4*)(sc_lo + row * 40 + seg * 8) = vl;
                }
            }
            __syncthreads();

            int r = lane & 15, quad = lane >> 4;
            int ibase = i0 + w * 32;      // this wave's 32 anchors (2 i-tiles)

            bf16x8 a_hi[2], a_lo[2];
            int gt_i[2][4];
            #pragma unroll
            for (int it = 0; it < 2; ++it) {
                int i = ibase + it * 16 + r;
                bf16x8 zh = {0, 0, 0, 0, 0, 0, 0, 0};
                a_hi[it] = zh; a_lo[it] = zh;
                if (i < M) {
                    a_hi[it] = *(const bf16x8*)(hi_g + ((size_t)b * N_ + i) * 32 + quad * 8);
                    a_lo[it] = *(const bf16x8*)(lo_g + ((size_t)b * N_ + i) * 32 + quad * 8);
                }
                #pragma unroll
                for (int r4 = 0; r4 < 4; ++r4) {
                    int ia = ibase + it * 16 + quad * 4 + r4;
                    gt_i[it][r4] = (ia < M) ? cgt[b * N_ + ia] : -2;
                }
            }

            float best[2][4];
            int cnt[2][4];
            #pragma unroll
            for (int it = 0; it < 2; ++it)
                #pragma unroll
                for (int r4 = 0; r4 < 4; ++r4) { best[it][r4] = -INFINITY; cnt[it][r4] = 0; }

            int jrows = min(TJ, M - j0);
            int ntile = (jrows + 15) >> 4;
            for (int jt = 0; jt < ntile; ++jt) {
                int gtj = sg[jt * 16 + r];
                bf16x8 bh = *(const bf16x8*)(sc_hi + (jt * 16 + r) * 40 + quad * 8);
                bf16x8 bl = *(const bf16x8*)(sc_lo + (jt * 16 + r) * 40 + quad * 8);
                bool jv = (gtj >= 0);
                #pragma unroll
                for (int it = 0; it < 2; ++it) {
                    f32x4 acc = {0.f, 0.f, 0.f, 0.f};
                    acc = __builtin_amdgcn_mfma_f32_16x16x32_bf16(a_hi[it], bh, acc, 0, 0, 0);
                    acc = __builtin_amdgcn_mfma_f32_16x16x32_bf16(a_hi[it], bl, acc, 0, 0, 0);
                    acc = __builtin_amdgcn_mfma_f32_16x16x32_bf16(a_lo[it], bh, acc, 0, 0, 0);
                    #pragma unroll
                    for (int r4 = 0; r4 < 4; ++r4) {
                        float s = acc[r4];
                        bool same = (gtj == gt_i[it][r4]);
                        float sm = (same || !jv) ? -INFINITY : s;
                        best[it][r4] = fmaxf(best[it][r4], sm);
                        cnt[it][r4] += same ? 1 : 0;   // self-pair incl.; fixed in combine
                    }
                }
            }

            #pragma unroll
            for (int it = 0; it < 2; ++it) {
                #pragma unroll
                for (int r4 = 0; r4 < 4; ++r4) {
                    float bb = best[it][r4];
                    int cc = cnt[it][r4];
                    #pragma unroll
                    for (int mk = 1; mk < 16; mk <<= 1) {
                        bb = fmaxf(bb, __shfl_xor(bb, mk));
                        cc += __shfl_xor(cc, mk);
                    }
                    if (r == 0) {
                        int ia = ibase + it * 16 + quad * 4 + r4;
                        if (ia < M) {
                            p_cnt[((size_t)b * N_ + ia) * NCHJ + jb] = (unsigned short)cc;
                            if (bb > -INFINITY) atomicMax(&bestArr[b * N_ + ia], fmap(bb));
                        }
                    }
                }
            }
            __syncthreads();   // LDS reused next unit
        }
    }

    grid.sync();

    // ======== Phase C: combine (one wave per anchor, register partials) ========
    float tv = 0.0f;
    int tc = 0;
    {
        int cumC[B_ + 1]; cumC[0] = 0;
        #pragma unroll
        for (int b = 0; b < B_; ++b) cumC[b + 1] = cumC[b] + (Mv[b] + 3) / 4;
        int totC = cumC[B_];
        for (int u = blockIdx.x; u < totC; u += gridDim.x) {
            int b = 0;
            while (u >= cumC[b + 1]) ++b;
            int g = u - cumC[b];
            int M = Mv[b];
            int i = g * 4 + w;            // this wave's anchor (wave-uniform)
            if (i < M) {
                int nchj = (M + TJ - 1) / TJ;
                int ich = i / TJ;
                const unsigned short* pc = p_cnt + ((size_t)b * N_ + i) * NCHJ;
                int c_s = 0;
                if (lane < nchj) c_s = (int)pc[lane] - (lane == ich ? 1 : 0);  // self removed
                int P = c_s;
                #pragma unroll
                for (int off = 1; off < 64; off <<= 1) {
                    int n = __shfl_up(P, off);
                    if (lane >= off) P += n;
                }
                int num_pos = __shfl(P, 63);
                unsigned bu = bestArr[b * N_ + i];
                if (num_pos >= 1 && bu != NEG_INF_MAPPED) {   // wave-uniform
                    float best = funmap(bu);
                    int orig = clist[b * N_ + i];
                    float uu = pos_rand[b * N_ + orig];
                    int pcx = (int)floorf(uu * (float)num_pos);   // matches jnp f32 math
                    int hi2 = num_pos - 1;
                    pcx = pcx < 0 ? 0 : (pcx > hi2 ? hi2 : pcx);
                    int target = pcx + 1;
                    unsigned long long selm = __ballot(P >= target);
                    int sstar = __ffsll((unsigned long long)selm) - 1;
                    int c0 = (sstar > 0) ? __shfl(P, sstar - 1) : 0;
                    int need = target - c0;       // wave-uniform, >= 1
                    int jstart = sstar * TJ;
                    int jend = min(jstart + TJ, M);
                    int ga = cgt[b * N_ + i];
                    int posj = -1;
                    #pragma unroll
                    for (int k = 0; k < 4; ++k) {
                        if (posj >= 0) continue;
                        int j = jstart + k * 64 + lane;
                        bool flg = (j < jend) && (cgt[b * N_ + j] == ga) && (j != i);
                        unsigned long long mk = __ballot(flg);
                        int tot = __popcll(mk);
                        if (need <= tot) {
                            int pfx = __popcll(mk & ((1ull << lane) - 1ull));
                            unsigned long long sel = __ballot(flg && (pfx == need - 1));
                            posj = jstart + k * 64 + (__ffsll((unsigned long long)sel) - 1);
                        } else {
                            need -= tot;
                        }
                    }
                    float part = 0.0f;
                    if (lane < 16) {
                        unsigned xh = ((const unsigned*)(hi_g + ((size_t)b * N_ + i) * 32))[lane];
                        unsigned xl = ((const unsigned*)(lo_g + ((size_t)b * N_ + i) * 32))[lane];
                        unsigned yh = ((const unsigned*)(hi_g + ((size_t)b * N_ + posj) * 32))[lane];
                        unsigned yl = ((const unsigned*)(lo_g + ((size_t)b * N_ + posj) * 32))[lane];
                        float a0, a1, b0, b1, c0f, c1f, d0, d1;
                        bf2x(xh, a0, a1); bf2x(xl, b0, b1);
                        bf2x(yh, c0f, c1f); bf2x(yl, d0, d1);
                        part = fmaf(a0 + b0, c0f + d0, (a1 + b1) * (c1f + d1));
                    }
                    #pragma unroll
                    for (int mk2 = 1; mk2 < 16; mk2 <<= 1) part += __shfl_xor(part, mk2);
                    float dot = part;
                    float pos_d = sqrtf(fmaxf(2.f - 2.f * dot, 0.f) + 1e-12f);
                    float neg_d = sqrtf(fmaxf(2.f - 2.f * best, 0.f) + 1e-12f);
                    if (lane == 0) {
                        tv += fmaxf(pos_d - neg_d + MARGIN_, 0.0f);
                        tc += 1;
                    }
                }
            }
        }
    }
    __syncthreads();
    if (lane == 0) { swv[w] = tv; swc[w] = tc; }
    __syncthreads();
    if (t == 0) {
        partV[blockIdx.x] = swv[0] + swv[1] + swv[2] + swv[3];
        partC[blockIdx.x] = swc[0] + swc[1] + swc[2] + swc[3];
    }

    grid.sync();

    // ======== Phase D: final reduction (block 0) ========
    if (blockIdx.x == 0) {
        float v = 0.0f; int c2 = 0;
        for (int k = t; k < (int)gridDim.x; k += 256) { v += partV[k]; c2 += partC[k]; }
        #pragma unroll
        for (int o = 32; o > 0; o >>= 1) {
            v += __shfl_down(v, o);
            c2 += __shfl_down(c2, o);
        }
        if (lane == 0) { swv[w] = v; swc[w] = c2; }
        __syncthreads();
        if (t == 0) {
            float T = swv[0] + swv[1] + swv[2] + swv[3];
            int C = swc[0] + swc[1] + swc[2] + swc[3];
            out[0] = (C > 0) ? (T / (float)C) : 0.0f;
        }
    }
}

// ---------------- launch ----------------
extern "C" void kernel_launch(void* const* d_in, const int* in_sizes, int n_in,
                              void* d_out, int out_size, void* d_ws, size_t ws_size,
                              hipStream_t stream) {
    const float* pred     = (const float*)d_in[0];
    const float* pos_rand = (const float*)d_in[1];
    const int*   gt       = (const int*)d_in[2];
    const int*   fg       = (const int*)d_in[3];
    float* outp = (float*)d_out;

    char* ws = (char*)d_ws;
    // layout (bytes):
    //   hi_g     : 0         .. 1,638,400   (B*N*32 bf16)
    //   lo_g     : 1,638,400 .. 3,276,800
    //   clist    : 3,276,800 .. 3,379,200   (B*N i32)
    //   cg       : 3,379,200 .. 3,481,600   (B*N i32)
    //   Marr     : 3,481,600 .. 3,481,664
    //   bestArr  : 3,482,688 .. 3,585,088   (B*N u32)
    //   p_cnt    : 3,585,088 .. 4,865,088   (B*N*NCHJ u16)
    //   partV    : 4,865,088 .. 4,867,136   (GRID_ f32)
    //   partC    : 4,867,136 .. 4,869,184   (GRID_ i32)
    unsigned short* hi_g    = (unsigned short*)(ws);
    unsigned short* lo_g    = (unsigned short*)(ws + 1638400);
    int*            clist   = (int*)(ws + 3276800);
    int*            cgt     = (int*)(ws + 3379200);
    int*            Marr    = (int*)(ws + 3481600);
    unsigned*       bestArr = (unsigned*)(ws + 3482688);
    unsigned short* p_cnt   = (unsigned short*)(ws + 3585088);
    float*          partV   = (float*)(ws + 4865088);
    int*            partC   = (int*)(ws + 4867136);

    void* kargs[] = {
        (void*)&pred, (void*)&gt, (void*)&fg, (void*)&pos_rand,
        (void*)&hi_g, (void*)&lo_g, (void*)&clist, (void*)&cgt,
        (void*)&Marr, (void*)&bestArr, (void*)&p_cnt,
        (void*)&partV, (void*)&partC, (void*)&outp
    };
    hipLaunchCooperativeKernel((const void*)k_mega, dim3(GRID_), dim3(256),
                               kargs, 0, stream);
}

// Round 9
// 120.100 us; speedup vs baseline: 2.2117x; 2.2117x over previous
//
#include <hip/hip_runtime.h>
#include <math.h>

// Problem constants (fixed by the reference setup)
#define B_ 4
#define N_ 6400
#define D_ 32
#define TJ 256          // j-chunk staged in LDS (k_pass), also combine chunking
#define NCHJ 25         // N_/TJ
#define TI 128          // anchors per k_pass block (4 waves x 2 i-tiles x 16)
#define CHUNK 256       // compaction chunk
#define NCC 25          // N_/CHUNK
#define CGRID 400       // combine blocks (small: bounds done-counter serialization)

typedef __attribute__((ext_vector_type(4))) float f32x4;
typedef __attribute__((ext_vector_type(8))) short bf16x8;

static constexpr float MARGIN_ = 0.3f;

// monotone float<->uint map so atomicMax(uint) == float max
__device__ __forceinline__ unsigned fmap(float f) {
    unsigned u = __float_as_uint(f);
    return (u & 0x80000000u) ? ~u : (u | 0x80000000u);
}
__device__ __forceinline__ float funmap(unsigned u) {
    return (u & 0x80000000u) ? __uint_as_float(u ^ 0x80000000u)
                             : __uint_as_float(~u);
}
#define NEG_INF_MAPPED 0x007FFFFFu   // fmap(-inf)

// round-to-nearest-even f32 -> bf16
__device__ __forceinline__ unsigned short f2bf(float f) {
    unsigned u = __float_as_uint(f);
    unsigned r = u + 0x7fffu + ((u >> 16) & 1u);
    return (unsigned short)(r >> 16);
}
__device__ __forceinline__ float bf2f(unsigned short h) {
    return __uint_as_float(((unsigned)h) << 16);
}
// unpack packed bf16 pair (elem even in low 16, odd in high 16)
__device__ __forceinline__ void bf2x(unsigned u, float& e0, float& e1) {
    e0 = __uint_as_float(u << 16);
    e1 = __uint_as_float(u & 0xffff0000u);
}

// ---------------- Kernel 1: self-contained prep (multi-wave chunk counting) ----------------
// grid (25, B). All 4 waves count 6-7 chunks each into LDS scnt[25] (was: wave 0
// serial over 25 — 3x shorter critical path). Then ballot-rank scatter + gather
// + normalize + bf16 hi/lo split. Also inits bestArr and resets done counter.
__global__ __launch_bounds__(256) void k_prep(const float* __restrict__ pred,
                                              const int* __restrict__ gt,
                                              const int* __restrict__ fg,
                                              unsigned short* __restrict__ hi_g,
                                              unsigned short* __restrict__ lo_g,
                                              int* __restrict__ clist,
                                              int* __restrict__ cg,
                                              int* __restrict__ Marr,
                                              unsigned* __restrict__ bestArr,
                                              unsigned* __restrict__ done) {
    int c = blockIdx.x, b = blockIdx.y;
    int t = threadIdx.x;
    int lane = t & 63, w = t >> 6;
    int idx = c * CHUNK + t;

    if (c == 0 && b == 0 && t == 0)
        __hip_atomic_store(done, 0u, __ATOMIC_RELAXED, __HIP_MEMORY_SCOPE_AGENT);

    bestArr[b * N_ + idx] = NEG_INF_MAPPED;

    // own-chunk ballot rank
    bool flag = fg[b * N_ + idx] != 0;
    unsigned long long m = __ballot(flag);
    int lp = __popcll(m & ((1ull << lane) - 1ull));
    __shared__ int wsh[4];
    __shared__ int scnt[NCC];
    if (lane == 0) wsh[w] = __popcll(m);

    // all 4 waves: count chunks w, w+4, w+8, ... (6-7 per wave)
    for (int cc = w; cc < NCC; cc += 4) {
        const int4 v = ((const int4*)(fg + (size_t)b * N_ + cc * CHUNK))[lane];
        int cnt = (v.x != 0) + (v.y != 0) + (v.z != 0) + (v.w != 0);
        #pragma unroll
        for (int o = 1; o < 64; o <<= 1) cnt += __shfl_xor(cnt, o);
        if (lane == 0) scnt[cc] = cnt;
    }
    __syncthreads();

    int pre = 0, tot = 0;
    #pragma unroll
    for (int cc = 0; cc < NCC; ++cc) {
        int s = scnt[cc];
        pre += (cc < c) ? s : 0;
        tot += s;
    }
    if (c == 0 && t == 0) Marr[b] = tot;
    if (!flag) return;

    int woff = 0;
    #pragma unroll
    for (int k = 0; k < 4; ++k) if (k < w) woff += wsh[k];
    int rank = pre + woff + lp;
    clist[b * N_ + rank] = idx;
    cg[b * N_ + rank] = gt[b * N_ + idx];

    const float4* s4 = (const float4*)(pred + ((size_t)b * N_ + idx) * D_);
    float f[32];
    float ssq = 0.0f;
    #pragma unroll
    for (int k = 0; k < 8; ++k) {
        float4 q = s4[k];
        f[k * 4] = q.x; f[k * 4 + 1] = q.y; f[k * 4 + 2] = q.z; f[k * 4 + 3] = q.w;
        ssq += q.x * q.x + q.y * q.y + q.z * q.z + q.w * q.w;
    }
    float inv = 1.0f / fmaxf(sqrtf(ssq), 1e-12f);
    unsigned hw[16], lw[16];
    #pragma unroll
    for (int k = 0; k < 16; ++k) {
        float x0 = f[2 * k] * inv, x1 = f[2 * k + 1] * inv;
        unsigned short h0 = f2bf(x0), h1 = f2bf(x1);
        unsigned short l0 = f2bf(x0 - bf2f(h0)), l1 = f2bf(x1 - bf2f(h1));
        hw[k] = (unsigned)h0 | ((unsigned)h1 << 16);
        lw[k] = (unsigned)l0 | ((unsigned)l1 << 16);
    }
    uint4* dh = (uint4*)(hi_g + ((size_t)b * N_ + rank) * 32);
    uint4* dl = (uint4*)(lo_g + ((size_t)b * N_ + rank) * 32);
    #pragma unroll
    for (int k = 0; k < 4; ++k) {
        dh[k] = make_uint4(hw[4 * k], hw[4 * k + 1], hw[4 * k + 2], hw[4 * k + 3]);
        dl[k] = make_uint4(lw[4 * k], lw[4 * k + 1], lw[4 * k + 2], lw[4 * k + 3]);
    }
}

// ---------------- Kernel 2: MFMA pair pass (verified since R3, unchanged) ----------------
// grid = (ceil(N/TI), ceil(N/TJ), B). Wave covers 2 i-tiles of 16 anchors.
// S-tile = 16x16 via mfma_f32_16x16x32_bf16, 3 terms (hi*hi + hi*lo + lo*hi).
// C/D layout: col = lane&15, row = (lane>>4)*4 + reg  [m89-verified].
__global__ __launch_bounds__(256) void k_pass(const unsigned short* __restrict__ hi_g,
                                              const unsigned short* __restrict__ lo_g,
                                              const int* __restrict__ cg,
                                              const int* __restrict__ Marr,
                                              unsigned short* __restrict__ p_cnt,
                                              unsigned* __restrict__ bestArr) {
    int b = blockIdx.z;
    int M = Marr[b];
    int i0 = blockIdx.x * TI;
    int j0 = blockIdx.y * TJ;
    if (i0 >= M || j0 >= M) return;   // block-uniform exit

    // LDS rows padded to 80 B (40 shorts)
    __shared__ __align__(16) unsigned short sc_hi[TJ * 40];  // 20 KB
    __shared__ __align__(16) unsigned short sc_lo[TJ * 40];  // 20 KB
    __shared__ int sg[TJ];
    int t = threadIdx.x;

    {
        int j = j0 + t;
        sg[t] = (j < M) ? cg[b * N_ + j] : -1;
    }
    {   // stage: thread -> (row = p*64 + t>>2, 16B seg = t&3); coalesced global reads
        int seg = t & 3, r0 = t >> 2;
        #pragma unroll
        for (int p = 0; p < 4; ++p) {
            int row = p * 64 + r0;
            int j = j0 + row;
            uint4 vh = make_uint4(0u, 0u, 0u, 0u), vl = make_uint4(0u, 0u, 0u, 0u);
            if (j < M) {
                vh = *(const uint4*)(hi_g + ((size_t)b * N_ + j) * 32 + seg * 8);
                vl = *(const uint4*)(lo_g + ((size_t)b * N_ + j) * 32 + seg * 8);
            }
            *(uint4*)(sc_hi + row * 40 + seg * 8) = vh;
            *(uint4*)(sc_lo + row * 40 + seg * 8) = vl;
        }
    }
    __syncthreads();

    int lane = t & 63, w = t >> 6;
    int r = lane & 15, quad = lane >> 4;
    int ib = i0 + w * 32;            // this wave's 32 anchors (2 i-tiles)

    bf16x8 a_hi[2], a_lo[2];
    int gt_i[2][4];
    #pragma unroll
    for (int it = 0; it < 2; ++it) {
        int i = ib + it * 16 + r;
        bf16x8 zh = {0, 0, 0, 0, 0, 0, 0, 0};
        a_hi[it] = zh; a_lo[it] = zh;
        if (i < M) {
            a_hi[it] = *(const bf16x8*)(hi_g + ((size_t)b * N_ + i) * 32 + quad * 8);
            a_lo[it] = *(const bf16x8*)(lo_g + ((size_t)b * N_ + i) * 32 + quad * 8);
        }
        #pragma unroll
        for (int r4 = 0; r4 < 4; ++r4) {
            int ia = ib + it * 16 + quad * 4 + r4;
            gt_i[it][r4] = (ia < M) ? cg[b * N_ + ia] : -2;
        }
    }

    float best[2][4];
    int cnt[2][4];
    #pragma unroll
    for (int it = 0; it < 2; ++it)
        #pragma unroll
        for (int r4 = 0; r4 < 4; ++r4) { best[it][r4] = -INFINITY; cnt[it][r4] = 0; }

    int jrows = min(TJ, M - j0);
    int ntile = (jrows + 15) >> 4;
    for (int jt = 0; jt < ntile; ++jt) {
        int gtj = sg[jt * 16 + r];
        bf16x8 bh = *(const bf16x8*)(sc_hi + (jt * 16 + r) * 40 + quad * 8);
        bf16x8 bl = *(const bf16x8*)(sc_lo + (jt * 16 + r) * 40 + quad * 8);
        bool jv = (gtj >= 0);
        #pragma unroll
        for (int it = 0; it < 2; ++it) {
            f32x4 acc = {0.f, 0.f, 0.f, 0.f};
            acc = __builtin_amdgcn_mfma_f32_16x16x32_bf16(a_hi[it], bh, acc, 0, 0, 0);
            acc = __builtin_amdgcn_mfma_f32_16x16x32_bf16(a_hi[it], bl, acc, 0, 0, 0);
            acc = __builtin_amdgcn_mfma_f32_16x16x32_bf16(a_lo[it], bh, acc, 0, 0, 0);
            #pragma unroll
            for (int r4 = 0; r4 < 4; ++r4) {
                float s = acc[r4];
                bool same = (gtj == gt_i[it][r4]);
                float sm = (same || !jv) ? -INFINITY : s;
                best[it][r4] = fmaxf(best[it][r4], sm);
                cnt[it][r4] += same ? 1 : 0;   // self-pair included; fixed in combine
            }
        }
    }

    #pragma unroll
    for (int it = 0; it < 2; ++it) {
        #pragma unroll
        for (int r4 = 0; r4 < 4; ++r4) {
            float bb = best[it][r4];
            int cc = cnt[it][r4];
            #pragma unroll
            for (int mk = 1; mk < 16; mk <<= 1) {
                bb = fmaxf(bb, __shfl_xor(bb, mk));
                cc += __shfl_xor(cc, mk);
            }
            if (r == 0) {
                int ia = ib + it * 16 + quad * 4 + r4;
                if (ia < M) {
                    p_cnt[((size_t)b * N_ + ia) * NCHJ + blockIdx.y] = (unsigned short)cc;
                    if (bb > -INFINITY) atomicMax(&bestArr[b * N_ + ia], fmap(bb));
                }
            }
        }
    }
}

// ---------------- Kernel 3: combine + fused finalization ----------------
// 1D grid of CGRID blocks, grid-striding anchor-groups (4 anchors/block-step,
// one wave per anchor). Per-block partials -> agent-scope stores; done-counter
// (single atomic per block); last block reduces all partials -> out[0].
__global__ __launch_bounds__(256) void k_combine(const unsigned short* __restrict__ hi_g,
                                                 const unsigned short* __restrict__ lo_g,
                                                 const int* __restrict__ cg,
                                                 const int* __restrict__ clist,
                                                 const int* __restrict__ Marr,
                                                 const float* __restrict__ pos_rand,
                                                 const unsigned short* __restrict__ p_cnt,
                                                 const unsigned* __restrict__ bestArr,
                                                 float* __restrict__ partV,
                                                 int* __restrict__ partC,
                                                 unsigned* __restrict__ done,
                                                 float* __restrict__ out) {
    int t = threadIdx.x;
    int w = t >> 6, lane = t & 63;

    int Mv[B_];
    int cum[B_ + 1]; cum[0] = 0;
    #pragma unroll
    for (int b = 0; b < B_; ++b) {
        Mv[b] = Marr[b];
        cum[b + 1] = cum[b] + (Mv[b] + 3) / 4;
    }
    int totC = cum[B_];

    float tv = 0.0f;
    int tc = 0;
    for (int u = blockIdx.x; u < totC; u += CGRID) {
        int b = 0;
        while (u >= cum[b + 1]) ++b;
        int g = u - cum[b];
        int M = Mv[b];
        int i = g * 4 + w;            // this wave's anchor (wave-uniform)
        if (i < M) {
            int nchj = (M + TJ - 1) / TJ;
            int ich = i / TJ;
            const unsigned short* pc = p_cnt + ((size_t)b * N_ + i) * NCHJ;
            int c_s = 0;
            if (lane < nchj) c_s = (int)pc[lane] - (lane == ich ? 1 : 0);  // self removed
            int P = c_s;
            #pragma unroll
            for (int off = 1; off < 64; off <<= 1) {
                int n = __shfl_up(P, off);
                if (lane >= off) P += n;
            }
            int num_pos = __shfl(P, 63);
            unsigned bu = bestArr[b * N_ + i];
            if (num_pos >= 1 && bu != NEG_INF_MAPPED) {   // wave-uniform
                float best = funmap(bu);
                int orig = clist[b * N_ + i];
                float uu = pos_rand[b * N_ + orig];
                int pcx = (int)floorf(uu * (float)num_pos);   // matches jnp f32 math
                int hi2 = num_pos - 1;
                pcx = pcx < 0 ? 0 : (pcx > hi2 ? hi2 : pcx);
                int target = pcx + 1;
                unsigned long long selm = __ballot(P >= target);
                int sstar = __ffsll((unsigned long long)selm) - 1;
                int c0 = (sstar > 0) ? __shfl(P, sstar - 1) : 0;
                int need = target - c0;       // wave-uniform, >= 1
                int jstart = sstar * TJ;
                int jend = min(jstart + TJ, M);
                int ga = cg[b * N_ + i];
                int posj = -1;
                #pragma unroll
                for (int k = 0; k < 4; ++k) {
                    if (posj >= 0) continue;
                    int j = jstart + k * 64 + lane;
                    bool flg = (j < jend) && (cg[b * N_ + j] == ga) && (j != i);
                    unsigned long long mk = __ballot(flg);
                    int tot = __popcll(mk);
                    if (need <= tot) {
                        int pfx = __popcll(mk & ((1ull << lane) - 1ull));
                        unsigned long long sel = __ballot(flg && (pfx == need - 1));
                        posj = jstart + k * 64 + (__ffsll((unsigned long long)sel) - 1);
                    } else {
                        need -= tot;
                    }
                }
                float part = 0.0f;
                if (lane < 16) {
                    unsigned xh = ((const unsigned*)(hi_g + ((size_t)b * N_ + i) * 32))[lane];
                    unsigned xl = ((const unsigned*)(lo_g + ((size_t)b * N_ + i) * 32))[lane];
                    unsigned yh = ((const unsigned*)(hi_g + ((size_t)b * N_ + posj) * 32))[lane];
                    unsigned yl = ((const unsigned*)(lo_g + ((size_t)b * N_ + posj) * 32))[lane];
                    float a0, a1, b0, b1, c0f, c1f, d0, d1;
                    bf2x(xh, a0, a1); bf2x(xl, b0, b1);
                    bf2x(yh, c0f, c1f); bf2x(yl, d0, d1);
                    part = fmaf(a0 + b0, c0f + d0, (a1 + b1) * (c1f + d1));
                }
                #pragma unroll
                for (int mk2 = 1; mk2 < 16; mk2 <<= 1) part += __shfl_xor(part, mk2);
                float dot = part;
                float pos_d = sqrtf(fmaxf(2.f - 2.f * dot, 0.f) + 1e-12f);
                float neg_d = sqrtf(fmaxf(2.f - 2.f * best, 0.f) + 1e-12f);
                if (lane == 0) {
                    tv += fmaxf(pos_d - neg_d + MARGIN_, 0.0f);
                    tc += 1;
                }
            }
        }
    }

    // block partial
    __shared__ float swv[4];
    __shared__ int swc[4];
    __shared__ int sLast;
    if (lane == 0) { swv[w] = tv; swc[w] = tc; }
    __syncthreads();
    if (t == 0) {
        float bv = swv[0] + swv[1] + swv[2] + swv[3];
        int bc = swc[0] + swc[1] + swc[2] + swc[3];
        __hip_atomic_store(&partV[blockIdx.x], bv, __ATOMIC_RELAXED, __HIP_MEMORY_SCOPE_AGENT);
        __hip_atomic_store(&partC[blockIdx.x], bc, __ATOMIC_RELAXED, __HIP_MEMORY_SCOPE_AGENT);
        unsigned old = __hip_atomic_fetch_add(done, 1u, __ATOMIC_ACQ_REL, __HIP_MEMORY_SCOPE_AGENT);
        sLast = (old == CGRID - 1) ? 1 : 0;
    }
    __syncthreads();

    if (sLast) {   // last finishing block reduces all partials
        float v = 0.0f; int c2 = 0;
        for (int k = t; k < CGRID; k += 256) {
            v += __hip_atomic_load(&partV[k], __ATOMIC_RELAXED, __HIP_MEMORY_SCOPE_AGENT);
            c2 += __hip_atomic_load(&partC[k], __ATOMIC_RELAXED, __HIP_MEMORY_SCOPE_AGENT);
        }
        #pragma unroll
        for (int o = 32; o > 0; o >>= 1) {
            v += __shfl_down(v, o);
            c2 += __shfl_down(c2, o);
        }
        if (lane == 0) { swv[w] = v; swc[w] = c2; }
        __syncthreads();
        if (t == 0) {
            float T = swv[0] + swv[1] + swv[2] + swv[3];
            int C = swc[0] + swc[1] + swc[2] + swc[3];
            out[0] = (C > 0) ? (T / (float)C) : 0.0f;
        }
    }
}

// ---------------- launch ----------------
extern "C" void kernel_launch(void* const* d_in, const int* in_sizes, int n_in,
                              void* d_out, int out_size, void* d_ws, size_t ws_size,
                              hipStream_t stream) {
    const float* pred     = (const float*)d_in[0];
    const float* pos_rand = (const float*)d_in[1];
    const int*   gt       = (const int*)d_in[2];
    const int*   fg       = (const int*)d_in[3];
    float* out = (float*)d_out;

    char* ws = (char*)d_ws;
    // layout (bytes):
    //   hi_g     : 0         .. 1,638,400   (B*N*32 bf16)
    //   lo_g     : 1,638,400 .. 3,276,800
    //   clist    : 3,276,800 .. 3,379,200   (B*N i32)
    //   cg       : 3,379,200 .. 3,481,600   (B*N i32)
    //   Marr     : 3,481,600 .. 3,481,664
    //   bestArr  : 3,482,688 .. 3,585,088   (B*N u32)
    //   p_cnt    : 3,585,088 .. 4,865,088   (B*N*NCHJ u16)
    //   partV    : 4,865,088 .. 4,866,688   (CGRID f32)
    //   partC    : 4,866,688 .. 4,868,288   (CGRID i32)
    //   done     : 4,868,288               (u32)
    unsigned short* hi_g    = (unsigned short*)(ws);
    unsigned short* lo_g    = (unsigned short*)(ws + 1638400);
    int*            clist   = (int*)(ws + 3276800);
    int*            cg      = (int*)(ws + 3379200);
    int*            Marr    = (int*)(ws + 3481600);
    unsigned*       bestArr = (unsigned*)(ws + 3482688);
    unsigned short* p_cnt   = (unsigned short*)(ws + 3585088);
    float*          partV   = (float*)(ws + 4865088);
    int*            partC   = (int*)(ws + 4866688);
    unsigned*       done    = (unsigned*)(ws + 4868288);

    dim3 gpr(NCC, B_);
    k_prep<<<gpr, 256, 0, stream>>>(pred, gt, fg, hi_g, lo_g, clist, cg, Marr, bestArr, done);
    dim3 gp((N_ + TI - 1) / TI, (N_ + TJ - 1) / TJ, B_);
    k_pass<<<gp, 256, 0, stream>>>(hi_g, lo_g, cg, Marr, p_cnt, bestArr);
    k_combine<<<CGRID, 256, 0, stream>>>(hi_g, lo_g, cg, clist, Marr, pos_rand,
                                         p_cnt, bestArr, partV, partC, done, out);
}

// Round 10
// 106.151 us; speedup vs baseline: 2.5023x; 1.1314x over previous
//
#include <hip/hip_runtime.h>
#include <math.h>

// Problem constants (fixed by the reference setup)
#define B_ 4
#define N_ 6400
#define D_ 32
#define TJ 256          // j-chunk staged in LDS (k_pass), also combine chunking
#define NCHJ 25         // N_/TJ
#define TI 128          // anchors per k_pass block (4 waves x 2 i-tiles x 16)
#define CHUNK 256       // compaction chunk
#define NCC 25          // N_/CHUNK

typedef __attribute__((ext_vector_type(4))) float f32x4;
typedef __attribute__((ext_vector_type(8))) short bf16x8;

static constexpr float MARGIN_ = 0.3f;

// monotone float<->uint map so atomicMax(uint) == float max
__device__ __forceinline__ unsigned fmap(float f) {
    unsigned u = __float_as_uint(f);
    return (u & 0x80000000u) ? ~u : (u | 0x80000000u);
}
__device__ __forceinline__ float funmap(unsigned u) {
    return (u & 0x80000000u) ? __uint_as_float(u ^ 0x80000000u)
                             : __uint_as_float(~u);
}
#define NEG_INF_MAPPED 0x007FFFFFu   // fmap(-inf)

// round-to-nearest-even f32 -> bf16
__device__ __forceinline__ unsigned short f2bf(float f) {
    unsigned u = __float_as_uint(f);
    unsigned r = u + 0x7fffu + ((u >> 16) & 1u);
    return (unsigned short)(r >> 16);
}
__device__ __forceinline__ float bf2f(unsigned short h) {
    return __uint_as_float(((unsigned)h) << 16);
}
// unpack packed bf16 pair (elem even in low 16, odd in high 16)
__device__ __forceinline__ void bf2x(unsigned u, float& e0, float& e1) {
    e0 = __uint_as_float(u << 16);
    e1 = __uint_as_float(u & 0xffff0000u);
}

// ---------------- Kernel 1: self-contained prep (multi-wave chunk counting) ----------------
// grid (25, B). All 4 waves count 6-7 chunks each into LDS scnt[25] (R9's
// improvement: 3x shorter critical path than wave-0-serial). Then ballot-rank
// scatter + gather + normalize + bf16 hi/lo split. Also inits bestArr.
__global__ __launch_bounds__(256) void k_prep(const float* __restrict__ pred,
                                              const int* __restrict__ gt,
                                              const int* __restrict__ fg,
                                              unsigned short* __restrict__ hi_g,
                                              unsigned short* __restrict__ lo_g,
                                              int* __restrict__ clist,
                                              int* __restrict__ cg,
                                              int* __restrict__ Marr,
                                              unsigned* __restrict__ bestArr) {
    int c = blockIdx.x, b = blockIdx.y;
    int t = threadIdx.x;
    int lane = t & 63, w = t >> 6;
    int idx = c * CHUNK + t;

    bestArr[b * N_ + idx] = NEG_INF_MAPPED;

    // own-chunk ballot rank
    bool flag = fg[b * N_ + idx] != 0;
    unsigned long long m = __ballot(flag);
    int lp = __popcll(m & ((1ull << lane) - 1ull));
    __shared__ int wsh[4];
    __shared__ int scnt[NCC];
    if (lane == 0) wsh[w] = __popcll(m);

    // all 4 waves: count chunks w, w+4, w+8, ... (6-7 per wave)
    for (int cc = w; cc < NCC; cc += 4) {
        const int4 v = ((const int4*)(fg + (size_t)b * N_ + cc * CHUNK))[lane];
        int cnt = (v.x != 0) + (v.y != 0) + (v.z != 0) + (v.w != 0);
        #pragma unroll
        for (int o = 1; o < 64; o <<= 1) cnt += __shfl_xor(cnt, o);
        if (lane == 0) scnt[cc] = cnt;
    }
    __syncthreads();

    int pre = 0, tot = 0;
    #pragma unroll
    for (int cc = 0; cc < NCC; ++cc) {
        int s = scnt[cc];
        pre += (cc < c) ? s : 0;
        tot += s;
    }
    if (c == 0 && t == 0) Marr[b] = tot;
    if (!flag) return;

    int woff = 0;
    #pragma unroll
    for (int k = 0; k < 4; ++k) if (k < w) woff += wsh[k];
    int rank = pre + woff + lp;
    clist[b * N_ + rank] = idx;
    cg[b * N_ + rank] = gt[b * N_ + idx];

    const float4* s4 = (const float4*)(pred + ((size_t)b * N_ + idx) * D_);
    float f[32];
    float ssq = 0.0f;
    #pragma unroll
    for (int k = 0; k < 8; ++k) {
        float4 q = s4[k];
        f[k * 4] = q.x; f[k * 4 + 1] = q.y; f[k * 4 + 2] = q.z; f[k * 4 + 3] = q.w;
        ssq += q.x * q.x + q.y * q.y + q.z * q.z + q.w * q.w;
    }
    float inv = 1.0f / fmaxf(sqrtf(ssq), 1e-12f);
    unsigned hw[16], lw[16];
    #pragma unroll
    for (int k = 0; k < 16; ++k) {
        float x0 = f[2 * k] * inv, x1 = f[2 * k + 1] * inv;
        unsigned short h0 = f2bf(x0), h1 = f2bf(x1);
        unsigned short l0 = f2bf(x0 - bf2f(h0)), l1 = f2bf(x1 - bf2f(h1));
        hw[k] = (unsigned)h0 | ((unsigned)h1 << 16);
        lw[k] = (unsigned)l0 | ((unsigned)l1 << 16);
    }
    uint4* dh = (uint4*)(hi_g + ((size_t)b * N_ + rank) * 32);
    uint4* dl = (uint4*)(lo_g + ((size_t)b * N_ + rank) * 32);
    #pragma unroll
    for (int k = 0; k < 4; ++k) {
        dh[k] = make_uint4(hw[4 * k], hw[4 * k + 1], hw[4 * k + 2], hw[4 * k + 3]);
        dl[k] = make_uint4(lw[4 * k], lw[4 * k + 1], lw[4 * k + 2], lw[4 * k + 3]);
    }
}

// ---------------- Kernel 2: MFMA pair pass (verified since R3, unchanged) ----------------
// grid = (ceil(N/TI), ceil(N/TJ), B). Wave covers 2 i-tiles of 16 anchors.
// S-tile = 16x16 via mfma_f32_16x16x32_bf16, 3 terms (hi*hi + hi*lo + lo*hi).
// C/D layout: col = lane&15, row = (lane>>4)*4 + reg  [m89-verified].
__global__ __launch_bounds__(256) void k_pass(const unsigned short* __restrict__ hi_g,
                                              const unsigned short* __restrict__ lo_g,
                                              const int* __restrict__ cg,
                                              const int* __restrict__ Marr,
                                              unsigned short* __restrict__ p_cnt,
                                              unsigned* __restrict__ bestArr) {
    int b = blockIdx.z;
    int M = Marr[b];
    int i0 = blockIdx.x * TI;
    int j0 = blockIdx.y * TJ;
    if (i0 >= M || j0 >= M) return;   // block-uniform exit

    // LDS rows padded to 80 B (40 shorts): 16-lane frag reads = 2-way banks (free)
    __shared__ __align__(16) unsigned short sc_hi[TJ * 40];  // 20 KB
    __shared__ __align__(16) unsigned short sc_lo[TJ * 40];  // 20 KB
    __shared__ int sg[TJ];
    int t = threadIdx.x;

    {
        int j = j0 + t;
        sg[t] = (j < M) ? cg[b * N_ + j] : -1;
    }
    {   // stage: thread -> (row = p*64 + t>>2, 16B seg = t&3); coalesced global reads
        int seg = t & 3, r0 = t >> 2;
        #pragma unroll
        for (int p = 0; p < 4; ++p) {
            int row = p * 64 + r0;
            int j = j0 + row;
            uint4 vh = make_uint4(0u, 0u, 0u, 0u), vl = make_uint4(0u, 0u, 0u, 0u);
            if (j < M) {
                vh = *(const uint4*)(hi_g + ((size_t)b * N_ + j) * 32 + seg * 8);
                vl = *(const uint4*)(lo_g + ((size_t)b * N_ + j) * 32 + seg * 8);
            }
            *(uint4*)(sc_hi + row * 40 + seg * 8) = vh;
            *(uint4*)(sc_lo + row * 40 + seg * 8) = vl;
        }
    }
    __syncthreads();

    int lane = t & 63, w = t >> 6;
    int r = lane & 15, quad = lane >> 4;
    int ib = i0 + w * 32;            // this wave's 32 anchors (2 i-tiles)

    bf16x8 a_hi[2], a_lo[2];
    int gt_i[2][4];
    #pragma unroll
    for (int it = 0; it < 2; ++it) {
        int i = ib + it * 16 + r;
        bf16x8 zh = {0, 0, 0, 0, 0, 0, 0, 0};
        a_hi[it] = zh; a_lo[it] = zh;
        if (i < M) {
            a_hi[it] = *(const bf16x8*)(hi_g + ((size_t)b * N_ + i) * 32 + quad * 8);
            a_lo[it] = *(const bf16x8*)(lo_g + ((size_t)b * N_ + i) * 32 + quad * 8);
        }
        #pragma unroll
        for (int r4 = 0; r4 < 4; ++r4) {
            int ia = ib + it * 16 + quad * 4 + r4;
            gt_i[it][r4] = (ia < M) ? cg[b * N_ + ia] : -2;
        }
    }

    float best[2][4];
    int cnt[2][4];
    #pragma unroll
    for (int it = 0; it < 2; ++it)
        #pragma unroll
        for (int r4 = 0; r4 < 4; ++r4) { best[it][r4] = -INFINITY; cnt[it][r4] = 0; }

    int jrows = min(TJ, M - j0);
    int ntile = (jrows + 15) >> 4;
    for (int jt = 0; jt < ntile; ++jt) {
        int gtj = sg[jt * 16 + r];
        bf16x8 bh = *(const bf16x8*)(sc_hi + (jt * 16 + r) * 40 + quad * 8);
        bf16x8 bl = *(const bf16x8*)(sc_lo + (jt * 16 + r) * 40 + quad * 8);
        bool jv = (gtj >= 0);
        #pragma unroll
        for (int it = 0; it < 2; ++it) {
            f32x4 acc = {0.f, 0.f, 0.f, 0.f};
            acc = __builtin_amdgcn_mfma_f32_16x16x32_bf16(a_hi[it], bh, acc, 0, 0, 0);
            acc = __builtin_amdgcn_mfma_f32_16x16x32_bf16(a_hi[it], bl, acc, 0, 0, 0);
            acc = __builtin_amdgcn_mfma_f32_16x16x32_bf16(a_lo[it], bh, acc, 0, 0, 0);
            #pragma unroll
            for (int r4 = 0; r4 < 4; ++r4) {
                float s = acc[r4];
                bool same = (gtj == gt_i[it][r4]);
                float sm = (same || !jv) ? -INFINITY : s;
                best[it][r4] = fmaxf(best[it][r4], sm);
                cnt[it][r4] += same ? 1 : 0;   // self-pair included; fixed in combine
            }
        }
    }

    #pragma unroll
    for (int it = 0; it < 2; ++it) {
        #pragma unroll
        for (int r4 = 0; r4 < 4; ++r4) {
            float bb = best[it][r4];
            int cc = cnt[it][r4];
            #pragma unroll
            for (int mk = 1; mk < 16; mk <<= 1) {
                bb = fmaxf(bb, __shfl_xor(bb, mk));
                cc += __shfl_xor(cc, mk);
            }
            if (r == 0) {
                int ia = ib + it * 16 + quad * 4 + r4;
                if (ia < M) {
                    p_cnt[((size_t)b * N_ + ia) * NCHJ + blockIdx.y] = (unsigned short)cc;
                    if (bb > -INFINITY) atomicMax(&bestArr[b * N_ + ia], fmap(bb));
                }
            }
        }
    }
}

// ---------------- Kernel 3: combine — one wave per anchor, no global atomics ----------------
// (R7 structure: 6400 fully-parallel blocks, per-anchor writes — best measured)
__global__ __launch_bounds__(256) void k_combine(const unsigned short* __restrict__ hi_g,
                                                 const unsigned short* __restrict__ lo_g,
                                                 const int* __restrict__ cg,
                                                 const int* __restrict__ clist,
                                                 const int* __restrict__ Marr,
                                                 const float* __restrict__ pos_rand,
                                                 const unsigned short* __restrict__ p_cnt,
                                                 const unsigned* __restrict__ bestArr,
                                                 float* __restrict__ cArr,
                                                 int* __restrict__ vArr) {
    int b = blockIdx.y;
    int M = Marr[b];
    int t = threadIdx.x;
    int w = t >> 6, lane = t & 63;
    int i = blockIdx.x * 4 + w;           // this wave's anchor (wave-uniform)

    if (i >= M) return;                    // wave-uniform

    float contrib = 0.0f;
    int vflag = 0;

    int nchj = (M + TJ - 1) / TJ;
    int ich = i / TJ;
    const unsigned short* pc = p_cnt + ((size_t)b * N_ + i) * NCHJ;
    int c_s = 0;
    if (lane < nchj) c_s = (int)pc[lane] - (lane == ich ? 1 : 0);  // self removed
    // inclusive 64-lane scan
    int P = c_s;
    #pragma unroll
    for (int off = 1; off < 64; off <<= 1) {
        int n = __shfl_up(P, off);
        if (lane >= off) P += n;
    }
    int num_pos = __shfl(P, 63);
    unsigned bu = bestArr[b * N_ + i];
    if (num_pos >= 1 && bu != NEG_INF_MAPPED) {   // wave-uniform
        float best = funmap(bu);
        int orig = clist[b * N_ + i];
        float u = pos_rand[b * N_ + orig];
        int pcx = (int)floorf(u * (float)num_pos);   // matches jnp f32 math
        int hi2 = num_pos - 1;
        pcx = pcx < 0 ? 0 : (pcx > hi2 ? hi2 : pcx);
        int target = pcx + 1;
        // first chunk where inclusive prefix reaches target
        unsigned long long selm = __ballot(P >= target);
        int sstar = __ffsll((unsigned long long)selm) - 1;
        int c0 = (sstar > 0) ? __shfl(P, sstar - 1) : 0;
        int need = target - c0;       // wave-uniform, >= 1
        int jstart = sstar * TJ;
        int jend = min(jstart + TJ, M);
        int ga = cg[b * N_ + i];
        int posj = -1;
        #pragma unroll
        for (int k = 0; k < 4; ++k) {
            if (posj >= 0) continue;
            int j = jstart + k * 64 + lane;
            bool flag = (j < jend) && (cg[b * N_ + j] == ga) && (j != i);
            unsigned long long mk = __ballot(flag);
            int tot = __popcll(mk);
            if (need <= tot) {
                int pfx = __popcll(mk & ((1ull << lane) - 1ull));
                unsigned long long sel = __ballot(flag && (pfx == need - 1));
                posj = jstart + k * 64 + (__ffsll((unsigned long long)sel) - 1);
            } else {
                need -= tot;
            }
        }
        // lane-parallel dot over the 16 packed-bf16 pairs (fp32 reconstruct)
        float part = 0.0f;
        if (lane < 16) {
            unsigned xh = ((const unsigned*)(hi_g + ((size_t)b * N_ + i) * 32))[lane];
            unsigned xl = ((const unsigned*)(lo_g + ((size_t)b * N_ + i) * 32))[lane];
            unsigned yh = ((const unsigned*)(hi_g + ((size_t)b * N_ + posj) * 32))[lane];
            unsigned yl = ((const unsigned*)(lo_g + ((size_t)b * N_ + posj) * 32))[lane];
            float a0, a1, b0, b1, c0f, c1f, d0, d1;
            bf2x(xh, a0, a1); bf2x(xl, b0, b1);
            bf2x(yh, c0f, c1f); bf2x(yl, d0, d1);
            part = fmaf(a0 + b0, c0f + d0, (a1 + b1) * (c1f + d1));
        }
        #pragma unroll
        for (int mk2 = 1; mk2 < 16; mk2 <<= 1) part += __shfl_xor(part, mk2);
        float dot = part;
        float pos_d = sqrtf(fmaxf(2.f - 2.f * dot, 0.f) + 1e-12f);
        float neg_d = sqrtf(fmaxf(2.f - 2.f * best, 0.f) + 1e-12f);
        contrib = fmaxf(pos_d - neg_d + MARGIN_, 0.0f);
        vflag = 1;
    }

    if (lane == 0) {
        cArr[b * N_ + i] = contrib;
        vArr[b * N_ + i] = vflag;
    }
}

// ---------------- Kernel 4: final reduction (single block) ----------------
__global__ __launch_bounds__(1024) void k_final(const float* __restrict__ cArr,
                                                const int* __restrict__ vArr,
                                                const int* __restrict__ Marr,
                                                float* __restrict__ out) {
    int tid = threadIdx.x;
    float tv = 0.0f;
    int tc = 0;
    #pragma unroll
    for (int b = 0; b < B_; ++b) {
        int M = Marr[b];
        for (int i = tid; i < M; i += 1024) {
            tv += cArr[b * N_ + i];
            tc += vArr[b * N_ + i];
        }
    }
    #pragma unroll
    for (int off = 32; off > 0; off >>= 1) {
        tv += __shfl_down(tv, off);
        tc += __shfl_down(tc, off);
    }
    __shared__ float sv[16];
    __shared__ int scnt[16];
    int lane = tid & 63, w = tid >> 6;
    if (lane == 0) { sv[w] = tv; scnt[w] = tc; }
    __syncthreads();
    if (tid == 0) {
        float T = 0.0f; int C = 0;
        #pragma unroll
        for (int k = 0; k < 16; ++k) { T += sv[k]; C += scnt[k]; }
        out[0] = (C > 0) ? (T / (float)C) : 0.0f;
    }
}

// ---------------- launch ----------------
extern "C" void kernel_launch(void* const* d_in, const int* in_sizes, int n_in,
                              void* d_out, int out_size, void* d_ws, size_t ws_size,
                              hipStream_t stream) {
    const float* pred     = (const float*)d_in[0];
    const float* pos_rand = (const float*)d_in[1];
    const int*   gt       = (const int*)d_in[2];
    const int*   fg       = (const int*)d_in[3];
    float* out = (float*)d_out;

    char* ws = (char*)d_ws;
    // layout (bytes):
    //   hi_g     : 0         .. 1,638,400   (B*N*32 bf16)
    //   lo_g     : 1,638,400 .. 3,276,800
    //   clist    : 3,276,800 .. 3,379,200   (B*N i32)
    //   cg       : 3,379,200 .. 3,481,600   (B*N i32)
    //   Marr     : 3,481,600 .. 3,481,664
    //   bestArr  : 3,482,688 .. 3,585,088   (B*N u32)
    //   p_cnt    : 3,585,088 .. 4,865,088   (B*N*NCHJ u16)
    //   cArr     : 4,865,088 .. 4,967,488   (B*N f32)
    //   vArr     : 4,967,488 .. 5,069,888   (B*N i32)
    unsigned short* hi_g    = (unsigned short*)(ws);
    unsigned short* lo_g    = (unsigned short*)(ws + 1638400);
    int*            clist   = (int*)(ws + 3276800);
    int*            cg      = (int*)(ws + 3379200);
    int*            Marr    = (int*)(ws + 3481600);
    unsigned*       bestArr = (unsigned*)(ws + 3482688);
    unsigned short* p_cnt   = (unsigned short*)(ws + 3585088);
    float*          cArr    = (float*)(ws + 4865088);
    int*            vArr    = (int*)(ws + 4967488);

    dim3 gpr(NCC, B_);
    k_prep<<<gpr, 256, 0, stream>>>(pred, gt, fg, hi_g, lo_g, clist, cg, Marr, bestArr);
    dim3 gp((N_ + TI - 1) / TI, (N_ + TJ - 1) / TJ, B_);
    k_pass<<<gp, 256, 0, stream>>>(hi_g, lo_g, cg, Marr, p_cnt, bestArr);
    dim3 gc((N_ + 3) / 4, B_);
    k_combine<<<gc, 256, 0, stream>>>(hi_g, lo_g, cg, clist, Marr, pos_rand, p_cnt, bestArr, cArr, vArr);
    k_final<<<1, 1024, 0, stream>>>(cArr, vArr, Marr, out);
}